// Round 3
// baseline (369.754 us; speedup 1.0000x reference)
//
#include <hip/hip_runtime.h>
#include <hip/hip_bf16.h>

#define D 128

__device__ __forceinline__ float bf2f(unsigned short u) {
    union { unsigned int i; float f; } c;
    c.i = ((unsigned int)u) << 16;
    return c.f;
}
__device__ __forceinline__ float bits2f(unsigned int i) {
    union { unsigned int i; float f; } c;
    c.i = i;
    return c.f;
}
__device__ __forceinline__ unsigned short f2bf(float f) {
    __hip_bfloat16 h = __float2bfloat16(f);
    return *(unsigned short*)&h;
}

// Probe dtypes at runtime (one wave). flags[0]=1 if x is fp32; flags[1]=1 if ei is int64.
__global__ __launch_bounds__(64) void probe_kernel(
    const unsigned short* __restrict__ x,
    const long long* __restrict__ ei64,
    int nNodes, int* __restrict__ flags)
{
    const int lane = threadIdx.x;
    int cnt = 0;
    for (int i = lane; i < 512; i += 64) {
        float v = bf2f(x[i]);
        if (!(fabsf(v) < 1e4f)) cnt++;   // NaN counts
    }
    unsigned long long m1 = __ballot(cnt > 0);
    long long v = ei64[lane];
    int bad = (v < 0 || v >= (long long)nNodes) ? 1 : 0;
    unsigned long long m2 = __ballot(bad);
    if (lane == 0) {
        flags[0] = (__popcll(m1) > 2) ? 1 : 0;
        flags[1] = (m2 == 0) ? 1 : 0;
    }
}

// ---------- GEMM: out = in @ W (+ b). Register-blocked 64-row tiles. ----------
// in_f32 / out_f32: 1 = fp32, 0 = bf16, -1 = follow flags[0].
__global__ __launch_bounds__(256) void gemm_kernel(
    const void* __restrict__ inv, const void* __restrict__ Wv,
    const void* __restrict__ bv, void* __restrict__ outv,
    int nNodes, const int* __restrict__ flags,
    int in_f32p, int out_f32p, int add_bias)
{
    __shared__ float Ws[D * D];   // 64 KB
    __shared__ float bs[D];

    const int xf32 = flags[0];
    const int in_f32  = (in_f32p  < 0) ? xf32 : in_f32p;
    const int out_f32 = (out_f32p < 0) ? xf32 : out_f32p;

    if (xf32) {   // W/b dtype follows x dtype
        const float* W = (const float*)Wv;
        for (int i = threadIdx.x; i < D * D; i += 256) Ws[i] = W[i];
        if (threadIdx.x < D)
            bs[threadIdx.x] = add_bias ? ((const float*)bv)[threadIdx.x] : 0.f;
    } else {
        const unsigned short* W = (const unsigned short*)Wv;
        for (int i = threadIdx.x; i < D * D; i += 256) Ws[i] = bf2f(W[i]);
        if (threadIdx.x < D)
            bs[threadIdx.x] = add_bias ? bf2f(((const unsigned short*)bv)[threadIdx.x]) : 0.f;
    }
    __syncthreads();

    const int cg = threadIdx.x & 31;   // col group (4 cols)
    const int rg = threadIdx.x >> 5;   // row group (8 rows)
    const int c = cg * 4;
    const int row0 = blockIdx.x * 64 + rg * 8;

    size_t rIdx[8];
    #pragma unroll
    for (int r = 0; r < 8; ++r) {
        int row = row0 + r;
        rIdx[r] = (size_t)(row < nNodes ? row : nNodes - 1);
    }

    float4 acc[8];
    #pragma unroll
    for (int r = 0; r < 8; ++r)
        acc[r] = make_float4(bs[c], bs[c + 1], bs[c + 2], bs[c + 3]);

    if (in_f32) {
        const float* in = (const float*)inv;
        for (int k = 0; k < D; k += 4) {
            float4 w0 = *(const float4*)&Ws[(k + 0) * D + c];
            float4 w1 = *(const float4*)&Ws[(k + 1) * D + c];
            float4 w2 = *(const float4*)&Ws[(k + 2) * D + c];
            float4 w3 = *(const float4*)&Ws[(k + 3) * D + c];
            #pragma unroll
            for (int r = 0; r < 8; ++r) {
                float4 a = *(const float4*)(in + rIdx[r] * D + k);
                acc[r].x += a.x * w0.x + a.y * w1.x + a.z * w2.x + a.w * w3.x;
                acc[r].y += a.x * w0.y + a.y * w1.y + a.z * w2.y + a.w * w3.y;
                acc[r].z += a.x * w0.z + a.y * w1.z + a.z * w2.z + a.w * w3.z;
                acc[r].w += a.x * w0.w + a.y * w1.w + a.z * w2.w + a.w * w3.w;
            }
        }
    } else {
        const unsigned short* in = (const unsigned short*)inv;
        for (int k = 0; k < D; k += 4) {
            float4 w0 = *(const float4*)&Ws[(k + 0) * D + c];
            float4 w1 = *(const float4*)&Ws[(k + 1) * D + c];
            float4 w2 = *(const float4*)&Ws[(k + 2) * D + c];
            float4 w3 = *(const float4*)&Ws[(k + 3) * D + c];
            #pragma unroll
            for (int r = 0; r < 8; ++r) {
                ushort4 u = *(const ushort4*)(in + rIdx[r] * D + k);
                float ax = bf2f(u.x), ay = bf2f(u.y), az = bf2f(u.z), aw = bf2f(u.w);
                acc[r].x += ax * w0.x + ay * w1.x + az * w2.x + aw * w3.x;
                acc[r].y += ax * w0.y + ay * w1.y + az * w2.y + aw * w3.y;
                acc[r].z += ax * w0.z + ay * w1.z + az * w2.z + aw * w3.z;
                acc[r].w += ax * w0.w + ay * w1.w + az * w2.w + aw * w3.w;
            }
        }
    }

    #pragma unroll
    for (int r = 0; r < 8; ++r) {
        int row = row0 + r;
        if (row >= nNodes) break;
        if (out_f32) {
            ((float4*)outv)[(size_t)row * 32 + cg] = acc[r];
        } else {
            ushort4 o;
            o.x = f2bf(acc[r].x); o.y = f2bf(acc[r].y);
            o.z = f2bf(acc[r].z); o.w = f2bf(acc[r].w);
            ((ushort4*)outv)[(size_t)row * 32 + cg] = o;
        }
    }
}

// ---------- bucketed CSR build ----------
// cnt padded: one counter per PAD ints (PAD=16 -> one per 64B line) to kill
// same-line atomic serialization. Bucket stores are nontemporal to avoid
// L2 allocate-evict churn on scattered 4B writes.
__global__ __launch_bounds__(256) void build_bucket(
    const void* __restrict__ eiv, int* __restrict__ cnt, int* __restrict__ bucket,
    int* __restrict__ ovfCnt, int* __restrict__ headOvf, int2* __restrict__ ovf,
    int nEdges, int nNodes, int CAP, int PAD, const int* __restrict__ flags)
{
    int e = blockIdx.x * 256 + threadIdx.x;
    if (e >= nEdges) return;
    int s, d;
    if (flags[1]) {
        const long long* ei = (const long long*)eiv;
        s = (int)ei[e];
        d = (int)ei[(size_t)nEdges + e];
    } else {
        const int* ei = (const int*)eiv;
        s = ei[e];
        d = ei[(size_t)nEdges + e];
    }
    int pos = atomicAdd(&cnt[(size_t)d * PAD], 1);
    if (pos < CAP) {
        __builtin_nontemporal_store(s, &bucket[(size_t)d * CAP + pos]);
    } else {
        int idx = atomicAdd(ovfCnt, 1);   // idx < nEdges guaranteed (ovf has E slots)
        int old = atomicExch(&headOvf[d], idx);
        ovf[idx] = make_int2(old, s);
    }
}

// ---------- gather y-rows via bucket list: no pointer-chase, 4 loads in flight ----------
__global__ __launch_bounds__(256) void gather_bucket(
    const unsigned int* __restrict__ yu,   // y as bf16 pairs (N x 64 uints)
    const int* __restrict__ cnt, const int* __restrict__ bucket,
    const int* __restrict__ headOvf, const int2* __restrict__ ovf,
    const void* __restrict__ bv, void* __restrict__ outv,
    int nNodes, int CAP, int PAD, const int* __restrict__ flags)
{
    int node = blockIdx.x * 4 + (threadIdx.x >> 6);
    if (node >= nNodes) return;
    const int lane = threadIdx.x & 63;
    const int xf32 = flags[0];
    const int n = __builtin_amdgcn_readfirstlane(node);

    const int deg = __builtin_amdgcn_readfirstlane(cnt[(size_t)n * PAD]);
    const int m = deg < CAP ? deg : CAP;

    float ax0 = 0.f, ax1 = 0.f, ax2 = 0.f, ax3 = 0.f;
    float ay0 = 0.f, ay1 = 0.f, ay2 = 0.f, ay3 = 0.f;

    const int* bp = bucket + (size_t)n * CAP;
    for (int j0 = 0; j0 < m; j0 += 64) {
        int jj = j0 + lane;
        int sv = (jj < m) ? bp[jj] : 0;   // one coalesced load of up to 64 src indices
        int cchunk = m - j0; if (cchunk > 64) cchunk = 64;
        int j = 0;
        for (; j + 4 <= cchunk; j += 4) {
            int s0 = __shfl(sv, j + 0);
            int s1 = __shfl(sv, j + 1);
            int s2 = __shfl(sv, j + 2);
            int s3 = __shfl(sv, j + 3);
            unsigned int u0 = yu[(size_t)s0 * 64 + lane];
            unsigned int u1 = yu[(size_t)s1 * 64 + lane];
            unsigned int u2 = yu[(size_t)s2 * 64 + lane];
            unsigned int u3 = yu[(size_t)s3 * 64 + lane];
            ax0 += bits2f(u0 << 16); ay0 += bits2f(u0 & 0xFFFF0000u);
            ax1 += bits2f(u1 << 16); ay1 += bits2f(u1 & 0xFFFF0000u);
            ax2 += bits2f(u2 << 16); ay2 += bits2f(u2 & 0xFFFF0000u);
            ax3 += bits2f(u3 << 16); ay3 += bits2f(u3 & 0xFFFF0000u);
        }
        for (; j < cchunk; ++j) {
            int s0 = __shfl(sv, j);
            unsigned int u0 = yu[(size_t)s0 * 64 + lane];
            ax0 += bits2f(u0 << 16); ay0 += bits2f(u0 & 0xFFFF0000u);
        }
    }

    if (deg > CAP) {   // rare overflow chain
        int cur = __builtin_amdgcn_readfirstlane(headOvf[n]);
        while (cur >= 0) {
            int2 t = ovf[cur];
            int s0 = __builtin_amdgcn_readfirstlane(t.y);
            unsigned int u0 = yu[(size_t)s0 * 64 + lane];
            ax0 += bits2f(u0 << 16); ay0 += bits2f(u0 & 0xFFFF0000u);
            cur = __builtin_amdgcn_readfirstlane(t.x);
        }
    }

    float ox = (ax0 + ax1) + (ax2 + ax3);
    float oy = (ay0 + ay1) + (ay2 + ay3);

    if (xf32) {
        float2 bb = ((const float2*)bv)[lane];
        float2 o; o.x = ox + bb.x; o.y = oy + bb.y;
        ((float2*)outv)[(size_t)node * 64 + lane] = o;
    } else {
        unsigned int ub = ((const unsigned int*)bv)[lane];
        ox += bits2f(ub << 16);
        oy += bits2f(ub & 0xFFFF0000u);
        unsigned int o = ((unsigned int)f2bf(ox)) | (((unsigned int)f2bf(oy)) << 16);
        ((unsigned int*)outv)[(size_t)node * 64 + lane] = o;
    }
}

// ---------- fallback scatter (atomics) if ws too small ----------
__global__ __launch_bounds__(256) void scatter_kernel(
    const void* __restrict__ xv, const void* __restrict__ eiv,
    float* __restrict__ agg, int nEdges, const int* __restrict__ flags)
{
    long long tid = (long long)blockIdx.x * 256 + threadIdx.x;
    int e = (int)(tid >> 5);
    if (e >= nEdges) return;
    int q = (int)tid & 31;

    const int xf32 = flags[0];
    int s, d;
    if (flags[1]) {
        const long long* ei = (const long long*)eiv;
        s = (int)ei[e]; d = (int)ei[(size_t)nEdges + e];
    } else {
        const int* ei = (const int*)eiv;
        s = ei[e]; d = ei[(size_t)nEdges + e];
    }
    float4 v;
    if (xf32) {
        v = ((const float4*)xv)[(size_t)s * 32 + q];
    } else {
        ushort4 u = ((const ushort4*)xv)[(size_t)s * 32 + q];
        v.x = bf2f(u.x); v.y = bf2f(u.y); v.z = bf2f(u.z); v.w = bf2f(u.w);
    }
    float* ap = agg + (size_t)d * D + q * 4;
    atomicAdd(ap + 0, v.x);
    atomicAdd(ap + 1, v.y);
    atomicAdd(ap + 2, v.z);
    atomicAdd(ap + 3, v.w);
}

static inline size_t alignup(size_t v, size_t a) { return (v + a - 1) & ~(a - 1); }

extern "C" void kernel_launch(void* const* d_in, const int* in_sizes, int n_in,
                              void* d_out, int out_size, void* d_ws, size_t ws_size,
                              hipStream_t stream) {
    const void* x  = d_in[0];
    const void* ei = d_in[1];
    const void* W  = d_in[2];
    const void* b  = d_in[3];

    const int nNodes = in_sizes[0] / D;
    const int nEdges = in_sizes[1] / 2;

    int* flags = (int*)d_ws;
    probe_kernel<<<1, 64, 0, stream>>>((const unsigned short*)x, (const long long*)ei,
                                       nNodes, flags);

    // fast path ws layout:
    // flags(512) | cnt[N*PAD] | ovfCnt(256B slot) | headOvf[N] | ovf[E] (int2) | bucket[N*CAP] | y[N*D] bf16
    int CAP = 0, PAD = 1;
    size_t off_cnt = 512, off_ovfc = 0, off_head = 0, off_ovf = 0, off_bucket = 0, off_y = 0;
    {
        const int caps[4] = {64, 64, 16, 16};
        const int pads[4] = {16,  1, 16,  1};
        for (int ci = 0; ci < 4; ++ci) {
            int cap = caps[ci], pad = pads[ci];
            size_t ocnt  = 512;
            size_t oovfc = alignup(ocnt + 4ull * pad * nNodes, 256);
            size_t ohead = oovfc + 256;
            size_t oovf  = alignup(ohead + 4ull * nNodes, 256);
            size_t obuck = alignup(oovf + 8ull * nEdges, 256);
            size_t oy    = alignup(obuck + 4ull * cap * nNodes, 512);
            size_t need  = oy + (size_t)nNodes * D * 2;   // y bf16
            if (ws_size >= need) {
                CAP = cap; PAD = pad; off_cnt = ocnt; off_ovfc = oovfc; off_head = ohead;
                off_ovf = oovf; off_bucket = obuck; off_y = oy;
                break;
            }
        }
    }

    const int eblocks = (nEdges + 255) / 256;
    const int mblocks = (nNodes + 63) / 64;

    if (CAP > 0) {
        int*  cnt     = (int*)((char*)d_ws + off_cnt);
        int*  ovfCnt  = (int*)((char*)d_ws + off_ovfc);
        int*  headOvf = (int*)((char*)d_ws + off_head);
        int2* ovf     = (int2*)((char*)d_ws + off_ovf);
        int*  bucket  = (int*)((char*)d_ws + off_bucket);
        void* y       = (void*)((char*)d_ws + off_y);

        // y = x @ W   (no bias; y stored bf16)
        gemm_kernel<<<mblocks, 256, 0, stream>>>(x, W, b, y, nNodes, flags,
                                                 /*in_f32*/-1, /*out_f32*/0, /*bias*/0);

        hipMemsetAsync(cnt, 0, off_head - off_cnt, stream);          // cnt = 0, ovfCnt = 0
        hipMemsetAsync(headOvf, 0xFF, 4ull * nNodes, stream);        // headOvf = -1
        build_bucket<<<eblocks, 256, 0, stream>>>(ei, cnt, bucket, ovfCnt, headOvf, ovf,
                                                  nEdges, nNodes, CAP, PAD, flags);

        int gblocks = (nNodes + 3) / 4;   // 1 wave/node, 4 waves/block
        gather_bucket<<<gblocks, 256, 0, stream>>>((const unsigned int*)y, cnt, bucket,
                                                   headOvf, ovf, b, d_out,
                                                   nNodes, CAP, PAD, flags);
    } else {
        // fallback: atomic scatter into fp32 agg, then out = agg @ W + b
        float* agg = (float*)((char*)d_ws + 512);
        hipMemsetAsync(agg, 0, (size_t)nNodes * D * sizeof(float), stream);
        long long total = (long long)nEdges * 32;
        int sblocks = (int)((total + 255) / 256);
        scatter_kernel<<<sblocks, 256, 0, stream>>>(x, ei, agg, nEdges, flags);
        gemm_kernel<<<mblocks, 256, 0, stream>>>(agg, W, b, d_out, nNodes, flags,
                                                 /*in_f32*/1, /*out_f32*/-1, /*bias*/1);
    }
}

// Round 4
// 346.469 us; speedup vs baseline: 1.0672x; 1.0672x over previous
//
#include <hip/hip_runtime.h>
#include <hip/hip_bf16.h>

#define D 128

__device__ __forceinline__ float bf2f(unsigned short u) {
    union { unsigned int i; float f; } c;
    c.i = ((unsigned int)u) << 16;
    return c.f;
}
__device__ __forceinline__ float bits2f(unsigned int i) {
    union { unsigned int i; float f; } c;
    c.i = i;
    return c.f;
}
__device__ __forceinline__ unsigned short f2bf(float f) {
    __hip_bfloat16 h = __float2bfloat16(f);
    return *(unsigned short*)&h;
}

// Probe dtypes at runtime (one wave). flags[0]=1 if x is fp32; flags[1]=1 if ei is int64.
__global__ __launch_bounds__(64) void probe_kernel(
    const unsigned short* __restrict__ x,
    const long long* __restrict__ ei64,
    int nNodes, int* __restrict__ flags)
{
    const int lane = threadIdx.x;
    int cnt = 0;
    for (int i = lane; i < 512; i += 64) {
        float v = bf2f(x[i]);
        if (!(fabsf(v) < 1e4f)) cnt++;   // NaN counts
    }
    unsigned long long m1 = __ballot(cnt > 0);
    long long v = ei64[lane];
    int bad = (v < 0 || v >= (long long)nNodes) ? 1 : 0;
    unsigned long long m2 = __ballot(bad);
    if (lane == 0) {
        flags[0] = (__popcll(m1) > 2) ? 1 : 0;
        flags[1] = (m2 == 0) ? 1 : 0;
    }
}

// ---------- standalone GEMM (fallback path only): out = in @ W (+ b) ----------
__global__ __launch_bounds__(256) void gemm_kernel(
    const void* __restrict__ inv, const void* __restrict__ Wv,
    const void* __restrict__ bv, void* __restrict__ outv,
    int nNodes, const int* __restrict__ flags,
    int in_f32p, int out_f32p, int add_bias)
{
    __shared__ float Ws[D * D];   // 64 KB
    __shared__ float bs[D];

    const int xf32 = flags[0];
    const int in_f32  = (in_f32p  < 0) ? xf32 : in_f32p;
    const int out_f32 = (out_f32p < 0) ? xf32 : out_f32p;

    if (xf32) {
        const float* W = (const float*)Wv;
        for (int i = threadIdx.x; i < D * D; i += 256) Ws[i] = W[i];
        if (threadIdx.x < D)
            bs[threadIdx.x] = add_bias ? ((const float*)bv)[threadIdx.x] : 0.f;
    } else {
        const unsigned short* W = (const unsigned short*)Wv;
        for (int i = threadIdx.x; i < D * D; i += 256) Ws[i] = bf2f(W[i]);
        if (threadIdx.x < D)
            bs[threadIdx.x] = add_bias ? bf2f(((const unsigned short*)bv)[threadIdx.x]) : 0.f;
    }
    __syncthreads();

    const int cg = threadIdx.x & 31;
    const int rg = threadIdx.x >> 5;
    const int c = cg * 4;
    const int row0 = blockIdx.x * 64 + rg * 8;

    size_t rIdx[8];
    #pragma unroll
    for (int r = 0; r < 8; ++r) {
        int row = row0 + r;
        rIdx[r] = (size_t)(row < nNodes ? row : nNodes - 1);
    }

    float4 acc[8];
    #pragma unroll
    for (int r = 0; r < 8; ++r)
        acc[r] = make_float4(bs[c], bs[c + 1], bs[c + 2], bs[c + 3]);

    if (in_f32) {
        const float* in = (const float*)inv;
        for (int k = 0; k < D; k += 4) {
            float4 w0 = *(const float4*)&Ws[(k + 0) * D + c];
            float4 w1 = *(const float4*)&Ws[(k + 1) * D + c];
            float4 w2 = *(const float4*)&Ws[(k + 2) * D + c];
            float4 w3 = *(const float4*)&Ws[(k + 3) * D + c];
            #pragma unroll
            for (int r = 0; r < 8; ++r) {
                float4 a = *(const float4*)(in + rIdx[r] * D + k);
                acc[r].x += a.x * w0.x + a.y * w1.x + a.z * w2.x + a.w * w3.x;
                acc[r].y += a.x * w0.y + a.y * w1.y + a.z * w2.y + a.w * w3.y;
                acc[r].z += a.x * w0.z + a.y * w1.z + a.z * w2.z + a.w * w3.z;
                acc[r].w += a.x * w0.w + a.y * w1.w + a.z * w2.w + a.w * w3.w;
            }
        }
    } else {
        const unsigned short* in = (const unsigned short*)inv;
        for (int k = 0; k < D; k += 4) {
            float4 w0 = *(const float4*)&Ws[(k + 0) * D + c];
            float4 w1 = *(const float4*)&Ws[(k + 1) * D + c];
            float4 w2 = *(const float4*)&Ws[(k + 2) * D + c];
            float4 w3 = *(const float4*)&Ws[(k + 3) * D + c];
            #pragma unroll
            for (int r = 0; r < 8; ++r) {
                ushort4 u = *(const ushort4*)(in + rIdx[r] * D + k);
                float ax = bf2f(u.x), ay = bf2f(u.y), az = bf2f(u.z), aw = bf2f(u.w);
                acc[r].x += ax * w0.x + ay * w1.x + az * w2.x + aw * w3.x;
                acc[r].y += ax * w0.y + ay * w1.y + az * w2.y + aw * w3.y;
                acc[r].z += ax * w0.z + ay * w1.z + az * w2.z + aw * w3.z;
                acc[r].w += ax * w0.w + ay * w1.w + az * w2.w + aw * w3.w;
            }
        }
    }

    #pragma unroll
    for (int r = 0; r < 8; ++r) {
        int row = row0 + r;
        if (row >= nNodes) break;
        if (out_f32) {
            ((float4*)outv)[(size_t)row * 32 + cg] = acc[r];
        } else {
            ushort4 o;
            o.x = f2bf(acc[r].x); o.y = f2bf(acc[r].y);
            o.z = f2bf(acc[r].z); o.w = f2bf(acc[r].w);
            ((ushort4*)outv)[(size_t)row * 32 + cg] = o;
        }
    }
}

// ---------- FUSED: gemm-role blocks (y = x@W, bf16 out) + build-role blocks ----------
// gemm and build are data-independent; fusing lets build's scattered-txn
// serialization (XCD coherence pipe) overlap gemm's VALU/LDS work.
// Ws packed bf16 (32 KB) so 4 blocks/CU fit; f32-dtype path reads W from global.
__global__ __launch_bounds__(256, 4) void fused_gemm_build(
    const void* __restrict__ xv, const void* __restrict__ Wv, void* __restrict__ yv,
    const void* __restrict__ eiv, int* __restrict__ cnt, int* __restrict__ bucket,
    int* __restrict__ ovfCnt, int* __restrict__ headOvf, int2* __restrict__ ovf,
    int nNodes, int nEdges, int CAP, int mblocks, const int* __restrict__ flags)
{
    __shared__ unsigned int WsU[D * D / 2];   // 32 KB: bf16-packed W (bf16 mode only)

    if ((int)blockIdx.x >= mblocks) {
        // ---- build role (no LDS, no syncthreads) ----
        int e = (blockIdx.x - mblocks) * 256 + threadIdx.x;
        if (e >= nEdges) return;
        int s, d;
        if (flags[1]) {
            const long long* ei = (const long long*)eiv;
            s = (int)ei[e];
            d = (int)ei[(size_t)nEdges + e];
        } else {
            const int* ei = (const int*)eiv;
            s = ei[e];
            d = ei[(size_t)nEdges + e];
        }
        int pos = atomicAdd(&cnt[d], 1);
        if (pos < CAP) {
            __builtin_nontemporal_store(s, &bucket[(size_t)d * CAP + pos]);
        } else {
            int idx = atomicAdd(ovfCnt, 1);
            int old = atomicExch(&headOvf[d], idx);
            ovf[idx] = make_int2(old, s);
        }
        return;
    }

    // ---- gemm role ----
    const int xf32 = flags[0];
    if (!xf32) {
        const unsigned int* Wp = (const unsigned int*)Wv;
        for (int i = threadIdx.x; i < D * D / 2; i += 256) WsU[i] = Wp[i];
    }
    __syncthreads();

    const int cg = threadIdx.x & 31;
    const int rg = threadIdx.x >> 5;
    const int c = cg * 4;
    const int row0 = blockIdx.x * 64 + rg * 8;

    size_t rIdx[8];
    #pragma unroll
    for (int r = 0; r < 8; ++r) {
        int row = row0 + r;
        rIdx[r] = (size_t)(row < nNodes ? row : nNodes - 1);
    }

    float4 acc[8];
    #pragma unroll
    for (int r = 0; r < 8; ++r) acc[r] = make_float4(0.f, 0.f, 0.f, 0.f);

    if (xf32) {
        const float* in = (const float*)xv;
        const float* Wg = (const float*)Wv;
        for (int k = 0; k < D; k += 4) {
            float4 w0 = *(const float4*)&Wg[(k + 0) * D + c];
            float4 w1 = *(const float4*)&Wg[(k + 1) * D + c];
            float4 w2 = *(const float4*)&Wg[(k + 2) * D + c];
            float4 w3 = *(const float4*)&Wg[(k + 3) * D + c];
            #pragma unroll
            for (int r = 0; r < 8; ++r) {
                float4 a = *(const float4*)(in + rIdx[r] * D + k);
                acc[r].x += a.x * w0.x + a.y * w1.x + a.z * w2.x + a.w * w3.x;
                acc[r].y += a.x * w0.y + a.y * w1.y + a.z * w2.y + a.w * w3.y;
                acc[r].z += a.x * w0.z + a.y * w1.z + a.z * w2.z + a.w * w3.z;
                acc[r].w += a.x * w0.w + a.y * w1.w + a.z * w2.w + a.w * w3.w;
            }
        }
    } else {
        const unsigned short* in = (const unsigned short*)xv;
        const int wbase = c >> 1;   // uint index of cols (c, c+1)
        for (int k = 0; k < D; k += 4) {
            uint2 p0 = *(const uint2*)&WsU[(k + 0) * 64 + wbase];
            uint2 p1 = *(const uint2*)&WsU[(k + 1) * 64 + wbase];
            uint2 p2 = *(const uint2*)&WsU[(k + 2) * 64 + wbase];
            uint2 p3 = *(const uint2*)&WsU[(k + 3) * 64 + wbase];
            float4 w0 = make_float4(bits2f(p0.x << 16), bits2f(p0.x & 0xFFFF0000u),
                                    bits2f(p0.y << 16), bits2f(p0.y & 0xFFFF0000u));
            float4 w1 = make_float4(bits2f(p1.x << 16), bits2f(p1.x & 0xFFFF0000u),
                                    bits2f(p1.y << 16), bits2f(p1.y & 0xFFFF0000u));
            float4 w2 = make_float4(bits2f(p2.x << 16), bits2f(p2.x & 0xFFFF0000u),
                                    bits2f(p2.y << 16), bits2f(p2.y & 0xFFFF0000u));
            float4 w3 = make_float4(bits2f(p3.x << 16), bits2f(p3.x & 0xFFFF0000u),
                                    bits2f(p3.y << 16), bits2f(p3.y & 0xFFFF0000u));
            #pragma unroll
            for (int r = 0; r < 8; ++r) {
                ushort4 u = *(const ushort4*)(in + rIdx[r] * D + k);
                float ax = bf2f(u.x), ay = bf2f(u.y), az = bf2f(u.z), aw = bf2f(u.w);
                acc[r].x += ax * w0.x + ay * w1.x + az * w2.x + aw * w3.x;
                acc[r].y += ax * w0.y + ay * w1.y + az * w2.y + aw * w3.y;
                acc[r].z += ax * w0.z + ay * w1.z + az * w2.z + aw * w3.z;
                acc[r].w += ax * w0.w + ay * w1.w + az * w2.w + aw * w3.w;
            }
        }
    }

    #pragma unroll
    for (int r = 0; r < 8; ++r) {
        int row = row0 + r;
        if (row >= nNodes) break;
        ushort4 o;
        o.x = f2bf(acc[r].x); o.y = f2bf(acc[r].y);
        o.z = f2bf(acc[r].z); o.w = f2bf(acc[r].w);
        ((ushort4*)yv)[(size_t)row * 32 + cg] = o;   // y always bf16
    }
}

// ---------- gather y-rows via bucket list: no pointer-chase, 4 loads in flight ----------
__global__ __launch_bounds__(256) void gather_bucket(
    const unsigned int* __restrict__ yu,   // y as bf16 pairs (N x 64 uints)
    const int* __restrict__ cnt, const int* __restrict__ bucket,
    const int* __restrict__ headOvf, const int2* __restrict__ ovf,
    const void* __restrict__ bv, void* __restrict__ outv,
    int nNodes, int CAP, const int* __restrict__ flags)
{
    int node = blockIdx.x * 4 + (threadIdx.x >> 6);
    if (node >= nNodes) return;
    const int lane = threadIdx.x & 63;
    const int xf32 = flags[0];
    const int n = __builtin_amdgcn_readfirstlane(node);

    const int deg = __builtin_amdgcn_readfirstlane(cnt[n]);
    const int m = deg < CAP ? deg : CAP;

    float ax0 = 0.f, ax1 = 0.f, ax2 = 0.f, ax3 = 0.f;
    float ay0 = 0.f, ay1 = 0.f, ay2 = 0.f, ay3 = 0.f;

    const int* bp = bucket + (size_t)n * CAP;
    for (int j0 = 0; j0 < m; j0 += 64) {
        int jj = j0 + lane;
        int sv = (jj < m) ? bp[jj] : 0;
        int cchunk = m - j0; if (cchunk > 64) cchunk = 64;
        int j = 0;
        for (; j + 4 <= cchunk; j += 4) {
            int s0 = __shfl(sv, j + 0);
            int s1 = __shfl(sv, j + 1);
            int s2 = __shfl(sv, j + 2);
            int s3 = __shfl(sv, j + 3);
            unsigned int u0 = yu[(size_t)s0 * 64 + lane];
            unsigned int u1 = yu[(size_t)s1 * 64 + lane];
            unsigned int u2 = yu[(size_t)s2 * 64 + lane];
            unsigned int u3 = yu[(size_t)s3 * 64 + lane];
            ax0 += bits2f(u0 << 16); ay0 += bits2f(u0 & 0xFFFF0000u);
            ax1 += bits2f(u1 << 16); ay1 += bits2f(u1 & 0xFFFF0000u);
            ax2 += bits2f(u2 << 16); ay2 += bits2f(u2 & 0xFFFF0000u);
            ax3 += bits2f(u3 << 16); ay3 += bits2f(u3 & 0xFFFF0000u);
        }
        for (; j < cchunk; ++j) {
            int s0 = __shfl(sv, j);
            unsigned int u0 = yu[(size_t)s0 * 64 + lane];
            ax0 += bits2f(u0 << 16); ay0 += bits2f(u0 & 0xFFFF0000u);
        }
    }

    if (deg > CAP) {   // rare overflow chain
        int cur = __builtin_amdgcn_readfirstlane(headOvf[n]);
        while (cur >= 0) {
            int2 t = ovf[cur];
            int s0 = __builtin_amdgcn_readfirstlane(t.y);
            unsigned int u0 = yu[(size_t)s0 * 64 + lane];
            ax0 += bits2f(u0 << 16); ay0 += bits2f(u0 & 0xFFFF0000u);
            cur = __builtin_amdgcn_readfirstlane(t.x);
        }
    }

    float ox = (ax0 + ax1) + (ax2 + ax3);
    float oy = (ay0 + ay1) + (ay2 + ay3);

    if (xf32) {
        float2 bb = ((const float2*)bv)[lane];
        float2 o; o.x = ox + bb.x; o.y = oy + bb.y;
        ((float2*)outv)[(size_t)node * 64 + lane] = o;
    } else {
        unsigned int ub = ((const unsigned int*)bv)[lane];
        ox += bits2f(ub << 16);
        oy += bits2f(ub & 0xFFFF0000u);
        unsigned int o = ((unsigned int)f2bf(ox)) | (((unsigned int)f2bf(oy)) << 16);
        ((unsigned int*)outv)[(size_t)node * 64 + lane] = o;
    }
}

// ---------- fallback scatter (atomics) if ws too small ----------
__global__ __launch_bounds__(256) void scatter_kernel(
    const void* __restrict__ xv, const void* __restrict__ eiv,
    float* __restrict__ agg, int nEdges, const int* __restrict__ flags)
{
    long long tid = (long long)blockIdx.x * 256 + threadIdx.x;
    int e = (int)(tid >> 5);
    if (e >= nEdges) return;
    int q = (int)tid & 31;

    const int xf32 = flags[0];
    int s, d;
    if (flags[1]) {
        const long long* ei = (const long long*)eiv;
        s = (int)ei[e]; d = (int)ei[(size_t)nEdges + e];
    } else {
        const int* ei = (const int*)eiv;
        s = ei[e]; d = ei[(size_t)nEdges + e];
    }
    float4 v;
    if (xf32) {
        v = ((const float4*)xv)[(size_t)s * 32 + q];
    } else {
        ushort4 u = ((const ushort4*)xv)[(size_t)s * 32 + q];
        v.x = bf2f(u.x); v.y = bf2f(u.y); v.z = bf2f(u.z); v.w = bf2f(u.w);
    }
    float* ap = agg + (size_t)d * D + q * 4;
    atomicAdd(ap + 0, v.x);
    atomicAdd(ap + 1, v.y);
    atomicAdd(ap + 2, v.z);
    atomicAdd(ap + 3, v.w);
}

static inline size_t alignup(size_t v, size_t a) { return (v + a - 1) & ~(a - 1); }

extern "C" void kernel_launch(void* const* d_in, const int* in_sizes, int n_in,
                              void* d_out, int out_size, void* d_ws, size_t ws_size,
                              hipStream_t stream) {
    const void* x  = d_in[0];
    const void* ei = d_in[1];
    const void* W  = d_in[2];
    const void* b  = d_in[3];

    const int nNodes = in_sizes[0] / D;
    const int nEdges = in_sizes[1] / 2;

    int* flags = (int*)d_ws;
    probe_kernel<<<1, 64, 0, stream>>>((const unsigned short*)x, (const long long*)ei,
                                       nNodes, flags);

    // fast path ws layout:
    // flags(512) | cnt[N] | ovfCnt(256B slot) | headOvf[N] | ovf[E] (int2) | bucket[N*CAP] | y[N*D] bf16
    int CAP = 0;
    size_t off_cnt = 512, off_ovfc = 0, off_head = 0, off_ovf = 0, off_bucket = 0, off_y = 0;
    {
        const int caps[2] = {64, 16};
        for (int ci = 0; ci < 2; ++ci) {
            int cap = caps[ci];
            size_t ocnt  = 512;
            size_t oovfc = alignup(ocnt + 4ull * nNodes, 256);
            size_t ohead = oovfc + 256;
            size_t oovf  = alignup(ohead + 4ull * nNodes, 256);
            size_t obuck = alignup(oovf + 8ull * nEdges, 256);
            size_t oy    = alignup(obuck + 4ull * cap * nNodes, 512);
            size_t need  = oy + (size_t)nNodes * D * 2;   // y bf16
            if (ws_size >= need) {
                CAP = cap; off_cnt = ocnt; off_ovfc = oovfc; off_head = ohead;
                off_ovf = oovf; off_bucket = obuck; off_y = oy;
                break;
            }
        }
    }

    const int eblocks = (nEdges + 255) / 256;
    const int mblocks = (nNodes + 63) / 64;

    if (CAP > 0) {
        int*  cnt     = (int*)((char*)d_ws + off_cnt);
        int*  ovfCnt  = (int*)((char*)d_ws + off_ovfc);
        int*  headOvf = (int*)((char*)d_ws + off_head);
        int2* ovf     = (int2*)((char*)d_ws + off_ovf);
        int*  bucket  = (int*)((char*)d_ws + off_bucket);
        void* y       = (void*)((char*)d_ws + off_y);

        hipMemsetAsync(cnt, 0, off_head - off_cnt, stream);          // cnt = 0, ovfCnt = 0
        hipMemsetAsync(headOvf, 0xFF, 4ull * nNodes, stream);        // headOvf = -1

        // fused: gemm-role blocks first (fill CUs), build-role blocks backfill
        fused_gemm_build<<<mblocks + eblocks, 256, 0, stream>>>(
            x, W, y, ei, cnt, bucket, ovfCnt, headOvf, ovf,
            nNodes, nEdges, CAP, mblocks, flags);

        int gblocks = (nNodes + 3) / 4;   // 1 wave/node, 4 waves/block
        gather_bucket<<<gblocks, 256, 0, stream>>>((const unsigned int*)y, cnt, bucket,
                                                   headOvf, ovf, b, d_out,
                                                   nNodes, CAP, flags);
    } else {
        // fallback: atomic scatter into fp32 agg, then out = agg @ W + b
        float* agg = (float*)((char*)d_ws + 512);
        hipMemsetAsync(agg, 0, (size_t)nNodes * D * sizeof(float), stream);
        long long total = (long long)nEdges * 32;
        int sblocks = (int)((total + 255) / 256);
        scatter_kernel<<<sblocks, 256, 0, stream>>>(x, ei, agg, nEdges, flags);
        gemm_kernel<<<mblocks, 256, 0, stream>>>(agg, W, b, d_out, nNodes, flags,
                                                 /*in_f32*/1, /*out_f32*/-1, /*bias*/1);
    }
}